// Round 1
// baseline (749.816 us; speedup 1.0000x reference)
//
#include <hip/hip_runtime.h>

// ---------------------------------------------------------------------------
// GraphTransformerWithPooling on MI355X (gfx950)
// Pipeline: 4x [GEMM(128x128)+bias -> CSR gather-sum], ReLU after pool 2 & 4,
// final GEMM(128x64)+bias. CSR (by dst) built once per launch; no fp atomics.
// ---------------------------------------------------------------------------

static inline int ceil_div(int a, int b) { return (a + b - 1) / b; }

// ---------------- CSR build ----------------

__global__ __launch_bounds__(256) void zero_ints(int* __restrict__ p, int n) {
    int i = blockIdx.x * 256 + threadIdx.x;
    if (i < n) p[i] = 0;
}

__global__ __launch_bounds__(256) void hist_kernel(const int* __restrict__ dst,
                                                   int* __restrict__ deg, int E) {
    int e = blockIdx.x * 256 + threadIdx.x;
    if (e < E) atomicAdd(&deg[dst[e]], 1);
}

// Exclusive scan over n = N+1 elements (deg[N] treated as 0).
__global__ __launch_bounds__(256) void scan_blocks_kernel(const int* __restrict__ deg,
                                                          int* __restrict__ rp,
                                                          int* __restrict__ partials,
                                                          int n, int N) {
    __shared__ int s[256];
    int tid = threadIdx.x;
    int i = blockIdx.x * 256 + tid;
    int v = (i < N) ? deg[i] : 0;
    s[tid] = v;
    __syncthreads();
    for (int off = 1; off < 256; off <<= 1) {
        int t = (tid >= off) ? s[tid - off] : 0;
        __syncthreads();
        s[tid] += t;
        __syncthreads();
    }
    if (i < n) rp[i] = s[tid] - v;          // exclusive within block
    if (tid == 255) partials[blockIdx.x] = s[255];
}

__global__ __launch_bounds__(256) void scan_partials_kernel(int* __restrict__ partials, int nb) {
    __shared__ int s[256];
    int tid = threadIdx.x;
    int v = (tid < nb) ? partials[tid] : 0;
    s[tid] = v;
    __syncthreads();
    for (int off = 1; off < 256; off <<= 1) {
        int t = (tid >= off) ? s[tid - off] : 0;
        __syncthreads();
        s[tid] += t;
        __syncthreads();
    }
    if (tid < nb) partials[tid] = s[tid] - v;  // exclusive
}

__global__ __launch_bounds__(256) void add_offsets_kernel(int* __restrict__ rp,
                                                          const int* __restrict__ partials,
                                                          int* __restrict__ cursor,
                                                          int n, int N) {
    int i = blockIdx.x * 256 + threadIdx.x;
    if (i < n) {
        int v = rp[i] + partials[blockIdx.x];
        rp[i] = v;
        if (i < N) cursor[i] = v;   // running cursor for bucket fill
    }
}

__global__ __launch_bounds__(256) void fill_kernel(const int* __restrict__ src,
                                                   const int* __restrict__ dst,
                                                   int* __restrict__ cursor,
                                                   int* __restrict__ es, int E) {
    int e = blockIdx.x * 256 + threadIdx.x;
    if (e < E) {
        int p = atomicAdd(&cursor[dst[e]], 1);
        es[p] = src[e];
    }
}

// ---------------- GEMM: Y[n,COLS] = X[n,128] @ W[128,COLS] + B ----------------
// 32-row x COLS tile per block, per-thread 4x4 register tile, W staged in LDS
// in KC-row chunks. TPB = 2*COLS (COLS=128 -> 256 thr; COLS=64 -> 128 thr).

template <int COLS, int KC>
__global__ __launch_bounds__(2 * COLS) void gemm_bias_kernel(const float* __restrict__ X,
                                                             const float* __restrict__ W,
                                                             const float* __restrict__ B,
                                                             float* __restrict__ Y, int n) {
    constexpr int TPB = 2 * COLS;
    constexpr int CG = COLS / 4;
    __shared__ float Wl[KC * COLS];
    __shared__ float Xl[32][132];   // +4 pad breaks bank aliasing for COLS=64 mapping

    int tid = threadIdx.x;
    int r0 = blockIdx.x * 32;

    // Stage X tile (32 rows x 128 cols) as float4, zero-padded past n.
    for (int idx = tid; idx < 32 * 32; idx += TPB) {
        int r = idx >> 5, c = idx & 31;
        float4 v = make_float4(0.f, 0.f, 0.f, 0.f);
        if (r0 + r < n) v = ((const float4*)(X + (size_t)(r0 + r) * 128))[c];
        *((float4*)&Xl[r][c * 4]) = v;
    }

    int cg = tid % CG, rg = tid / CG;
    int col = cg * 4, row = rg * 4;
    float acc[4][4] = {};

    for (int kc = 0; kc < 128; kc += KC) {
        __syncthreads();   // Xl ready (first iter) / Wl consumers done (later iters)
        for (int idx = tid; idx < KC * COLS / 4; idx += TPB) {
            ((float4*)Wl)[idx] = ((const float4*)(W + (size_t)kc * COLS))[idx];
        }
        __syncthreads();
        for (int k = 0; k < KC; k += 4) {
            float4 w0 = *((float4*)&Wl[(k + 0) * COLS + col]);
            float4 w1 = *((float4*)&Wl[(k + 1) * COLS + col]);
            float4 w2 = *((float4*)&Wl[(k + 2) * COLS + col]);
            float4 w3 = *((float4*)&Wl[(k + 3) * COLS + col]);
#pragma unroll
            for (int r = 0; r < 4; ++r) {
                float4 xv = *((float4*)&Xl[row + r][kc + k]);
                acc[r][0] += xv.x * w0.x + xv.y * w1.x + xv.z * w2.x + xv.w * w3.x;
                acc[r][1] += xv.x * w0.y + xv.y * w1.y + xv.z * w2.y + xv.w * w3.y;
                acc[r][2] += xv.x * w0.z + xv.y * w1.z + xv.z * w2.z + xv.w * w3.z;
                acc[r][3] += xv.x * w0.w + xv.y * w1.w + xv.z * w2.w + xv.w * w3.w;
            }
        }
    }

    float4 bb = *((const float4*)(B + col));
#pragma unroll
    for (int r = 0; r < 4; ++r) {
        int gr = r0 + row + r;
        if (gr < n) {
            float4 o = make_float4(acc[r][0] + bb.x, acc[r][1] + bb.y,
                                   acc[r][2] + bb.z, acc[r][3] + bb.w);
            *((float4*)(Y + (size_t)gr * COLS + col)) = o;
        }
    }
}

// ---------------- Aggregate: H[i,:] = sum_{e in CSR row i} M[es[e],:] ----------------
// 32 lanes per node (float4 over D=128), 8 nodes per 256-thread block.

__global__ __launch_bounds__(256) void aggregate_kernel(const float* __restrict__ M,
                                                        const int* __restrict__ rp,
                                                        const int* __restrict__ es,
                                                        float* __restrict__ H,
                                                        int n, int do_relu) {
    int node = blockIdx.x * 8 + (threadIdx.x >> 5);
    int lane = threadIdx.x & 31;
    if (node >= n) return;
    int beg = rp[node], end = rp[node + 1];
    float4 acc = make_float4(0.f, 0.f, 0.f, 0.f);
    for (int e = beg; e < end; ++e) {
        int s = es[e];
        float4 v = ((const float4*)(M + (size_t)s * 128))[lane];
        acc.x += v.x; acc.y += v.y; acc.z += v.z; acc.w += v.w;
    }
    if (do_relu) {
        acc.x = fmaxf(acc.x, 0.f);
        acc.y = fmaxf(acc.y, 0.f);
        acc.z = fmaxf(acc.z, 0.f);
        acc.w = fmaxf(acc.w, 0.f);
    }
    ((float4*)(H + (size_t)node * 128))[lane] = acc;
}

// ---------------- Launch ----------------

extern "C" void kernel_launch(void* const* d_in, const int* in_sizes, int n_in,
                              void* d_out, int out_size, void* d_ws, size_t ws_size,
                              hipStream_t stream) {
    const float* x    = (const float*)d_in[0];
    const int*   ei   = (const int*)d_in[1];
    const float* W1   = (const float*)d_in[2];
    const float* b1   = (const float*)d_in[3];
    const float* W2   = (const float*)d_in[4];
    const float* b2   = (const float*)d_in[5];
    const float* Wout = (const float*)d_in[6];
    const float* bout = (const float*)d_in[7];
    float*       out  = (float*)d_out;

    const int N = in_sizes[0] / 128;
    const int E = in_sizes[1] / 2;
    const int* src = ei;
    const int* dst = ei + E;

    // Workspace carve-up (all regions fully written before read).
    char* ws = (char*)d_ws;
    auto take = [&](size_t bytes) {
        char* p = ws;
        ws += (bytes + 255) & ~(size_t)255;
        return p;
    };
    float* m   = (float*)take((size_t)N * 128 * sizeof(float));
    float* hA  = (float*)take((size_t)N * 128 * sizeof(float));
    float* hB  = (float*)take((size_t)N * 128 * sizeof(float));
    int* rp      = (int*)take((size_t)(N + 1) * sizeof(int));
    int* cursor  = (int*)take((size_t)N * sizeof(int));
    int* es      = (int*)take((size_t)E * sizeof(int));
    int* partials = (int*)take(4096);

    // ---- CSR build (by dst) ----
    zero_ints<<<ceil_div(N, 256), 256, 0, stream>>>(cursor, N);   // cursor doubles as deg
    hist_kernel<<<ceil_div(E, 256), 256, 0, stream>>>(dst, cursor, E);
    int nScan = ceil_div(N + 1, 256);   // 196 for N=50000 (fits single-block partial scan)
    scan_blocks_kernel<<<nScan, 256, 0, stream>>>(cursor, rp, partials, N + 1, N);
    scan_partials_kernel<<<1, 256, 0, stream>>>(partials, nScan);
    add_offsets_kernel<<<nScan, 256, 0, stream>>>(rp, partials, cursor, N + 1, N);
    fill_kernel<<<ceil_div(E, 256), 256, 0, stream>>>(src, dst, cursor, es, E);

    // ---- Pipeline ----
    const int gemm_grid = ceil_div(N, 32);
    const int agg_grid  = ceil_div(N, 8);

    gemm_bias_kernel<128, 64><<<gemm_grid, 256, 0, stream>>>(x, W1, b1, m, N);
    aggregate_kernel<<<agg_grid, 256, 0, stream>>>(m, rp, es, hA, N, 0);

    gemm_bias_kernel<128, 64><<<gemm_grid, 256, 0, stream>>>(hA, W1, b1, m, N);
    aggregate_kernel<<<agg_grid, 256, 0, stream>>>(m, rp, es, hB, N, 1);   // ReLU

    gemm_bias_kernel<128, 64><<<gemm_grid, 256, 0, stream>>>(hB, W2, b2, m, N);
    aggregate_kernel<<<agg_grid, 256, 0, stream>>>(m, rp, es, hA, N, 0);

    gemm_bias_kernel<128, 64><<<gemm_grid, 256, 0, stream>>>(hA, W2, b2, m, N);
    aggregate_kernel<<<agg_grid, 256, 0, stream>>>(m, rp, es, hB, N, 1);   // ReLU

    gemm_bias_kernel<64, 128><<<gemm_grid, 128, 0, stream>>>(hB, Wout, bout, out, N);
}

// Round 2
// 505.613 us; speedup vs baseline: 1.4830x; 1.4830x over previous
//
#include <hip/hip_runtime.h>

// ---------------------------------------------------------------------------
// GraphTransformerWithPooling on MI355X (gfx950)
// Pipeline: 4x [GEMM(128x128)+bias -> CSR gather-sum], ReLU after pool 2 & 4,
// final GEMM(128x64)+bias. CSR (by dst) built once per launch; no fp atomics.
// R2: spill-free GEMM — KC=32, bounded unrolling (R1 had VGPR=256 + 105 MB
// spill stores per dispatch from full k-loop unroll hoisting Wl loads).
// ---------------------------------------------------------------------------

static inline int ceil_div(int a, int b) { return (a + b - 1) / b; }

// ---------------- CSR build ----------------

__global__ __launch_bounds__(256) void zero_ints(int* __restrict__ p, int n) {
    int i = blockIdx.x * 256 + threadIdx.x;
    if (i < n) p[i] = 0;
}

__global__ __launch_bounds__(256) void hist_kernel(const int* __restrict__ dst,
                                                   int* __restrict__ deg, int E) {
    int e = blockIdx.x * 256 + threadIdx.x;
    if (e < E) atomicAdd(&deg[dst[e]], 1);
}

// Exclusive scan over n = N+1 elements (deg[N] treated as 0).
__global__ __launch_bounds__(256) void scan_blocks_kernel(const int* __restrict__ deg,
                                                          int* __restrict__ rp,
                                                          int* __restrict__ partials,
                                                          int n, int N) {
    __shared__ int s[256];
    int tid = threadIdx.x;
    int i = blockIdx.x * 256 + tid;
    int v = (i < N) ? deg[i] : 0;
    s[tid] = v;
    __syncthreads();
    for (int off = 1; off < 256; off <<= 1) {
        int t = (tid >= off) ? s[tid - off] : 0;
        __syncthreads();
        s[tid] += t;
        __syncthreads();
    }
    if (i < n) rp[i] = s[tid] - v;          // exclusive within block
    if (tid == 255) partials[blockIdx.x] = s[255];
}

__global__ __launch_bounds__(256) void scan_partials_kernel(int* __restrict__ partials, int nb) {
    __shared__ int s[256];
    int tid = threadIdx.x;
    int v = (tid < nb) ? partials[tid] : 0;
    s[tid] = v;
    __syncthreads();
    for (int off = 1; off < 256; off <<= 1) {
        int t = (tid >= off) ? s[tid - off] : 0;
        __syncthreads();
        s[tid] += t;
        __syncthreads();
    }
    if (tid < nb) partials[tid] = s[tid] - v;  // exclusive
}

__global__ __launch_bounds__(256) void add_offsets_kernel(int* __restrict__ rp,
                                                          const int* __restrict__ partials,
                                                          int* __restrict__ cursor,
                                                          int n, int N) {
    int i = blockIdx.x * 256 + threadIdx.x;
    if (i < n) {
        int v = rp[i] + partials[blockIdx.x];
        rp[i] = v;
        if (i < N) cursor[i] = v;   // running cursor for bucket fill
    }
}

__global__ __launch_bounds__(256) void fill_kernel(const int* __restrict__ src,
                                                   const int* __restrict__ dst,
                                                   int* __restrict__ cursor,
                                                   int* __restrict__ es, int E) {
    int e = blockIdx.x * 256 + threadIdx.x;
    if (e < E) {
        int p = atomicAdd(&cursor[dst[e]], 1);
        es[p] = src[e];
    }
}

// ---------------- GEMM: Y[n,COLS] = X[n,128] @ W[128,COLS] + B ----------------
// 32-row x COLS tile per block, per-thread 4x4 register tile, W staged in LDS
// in KC-row chunks. TPB = 2*COLS. Unrolling is bounded explicitly: R1 showed
// unbounded unroll hoists all Wl loads -> 256 VGPR -> 105 MB spill/dispatch.

template <int COLS, int KC>
__global__ __launch_bounds__(2 * COLS) void gemm_bias_kernel(const float* __restrict__ X,
                                                             const float* __restrict__ W,
                                                             const float* __restrict__ B,
                                                             float* __restrict__ Y, int n) {
    constexpr int TPB = 2 * COLS;
    constexpr int CG = COLS / 4;
    __shared__ float Wl[KC * COLS];
    __shared__ float Xl[32][132];   // pad keeps rows offset, 16B-aligned float4 slots

    int tid = threadIdx.x;
    int r0 = blockIdx.x * 32;

    // Stage X tile (32 rows x 128 cols) as float4, zero-padded past n.
    for (int idx = tid; idx < 32 * 32; idx += TPB) {
        int r = idx >> 5, c = idx & 31;
        float4 v = make_float4(0.f, 0.f, 0.f, 0.f);
        if (r0 + r < n) v = ((const float4*)(X + (size_t)(r0 + r) * 128))[c];
        *((float4*)&Xl[r][c * 4]) = v;
    }

    int cg = tid % CG, rg = tid / CG;
    int col = cg * 4, row = rg * 4;
    float acc[4][4] = {};

#pragma unroll 1   // do NOT hoist W staging across chunks
    for (int kc = 0; kc < 128; kc += KC) {
        __syncthreads();   // Xl ready (first iter) / Wl consumers done (later iters)
        for (int idx = tid; idx < KC * COLS / 4; idx += TPB) {
            ((float4*)Wl)[idx] = ((const float4*)(W + (size_t)kc * COLS))[idx];
        }
        __syncthreads();
#pragma unroll 2   // bound live Wl-load registers (~32 floats), no spill
        for (int k = 0; k < KC; k += 4) {
            float4 w0 = *((float4*)&Wl[(k + 0) * COLS + col]);
            float4 w1 = *((float4*)&Wl[(k + 1) * COLS + col]);
            float4 w2 = *((float4*)&Wl[(k + 2) * COLS + col]);
            float4 w3 = *((float4*)&Wl[(k + 3) * COLS + col]);
#pragma unroll
            for (int r = 0; r < 4; ++r) {
                float4 xv = *((float4*)&Xl[row + r][kc + k]);
                acc[r][0] += xv.x * w0.x + xv.y * w1.x + xv.z * w2.x + xv.w * w3.x;
                acc[r][1] += xv.x * w0.y + xv.y * w1.y + xv.z * w2.y + xv.w * w3.y;
                acc[r][2] += xv.x * w0.z + xv.y * w1.z + xv.z * w2.z + xv.w * w3.z;
                acc[r][3] += xv.x * w0.w + xv.y * w1.w + xv.z * w2.w + xv.w * w3.w;
            }
        }
    }

    float4 bb = *((const float4*)(B + col));
#pragma unroll
    for (int r = 0; r < 4; ++r) {
        int gr = r0 + row + r;
        if (gr < n) {
            float4 o = make_float4(acc[r][0] + bb.x, acc[r][1] + bb.y,
                                   acc[r][2] + bb.z, acc[r][3] + bb.w);
            *((float4*)(Y + (size_t)gr * COLS + col)) = o;
        }
    }
}

// ---------------- Aggregate: H[i,:] = sum_{e in CSR row i} M[es[e],:] ----------------
// 32 lanes per node (float4 over D=128), 8 nodes per 256-thread block.

__global__ __launch_bounds__(256) void aggregate_kernel(const float* __restrict__ M,
                                                        const int* __restrict__ rp,
                                                        const int* __restrict__ es,
                                                        float* __restrict__ H,
                                                        int n, int do_relu) {
    int node = blockIdx.x * 8 + (threadIdx.x >> 5);
    int lane = threadIdx.x & 31;
    if (node >= n) return;
    int beg = rp[node], end = rp[node + 1];
    float4 acc = make_float4(0.f, 0.f, 0.f, 0.f);
    for (int e = beg; e < end; ++e) {
        int s = es[e];
        float4 v = ((const float4*)(M + (size_t)s * 128))[lane];
        acc.x += v.x; acc.y += v.y; acc.z += v.z; acc.w += v.w;
    }
    if (do_relu) {
        acc.x = fmaxf(acc.x, 0.f);
        acc.y = fmaxf(acc.y, 0.f);
        acc.z = fmaxf(acc.z, 0.f);
        acc.w = fmaxf(acc.w, 0.f);
    }
    ((float4*)(H + (size_t)node * 128))[lane] = acc;
}

// ---------------- Launch ----------------

extern "C" void kernel_launch(void* const* d_in, const int* in_sizes, int n_in,
                              void* d_out, int out_size, void* d_ws, size_t ws_size,
                              hipStream_t stream) {
    const float* x    = (const float*)d_in[0];
    const int*   ei   = (const int*)d_in[1];
    const float* W1   = (const float*)d_in[2];
    const float* b1   = (const float*)d_in[3];
    const float* W2   = (const float*)d_in[4];
    const float* b2   = (const float*)d_in[5];
    const float* Wout = (const float*)d_in[6];
    const float* bout = (const float*)d_in[7];
    float*       out  = (float*)d_out;

    const int N = in_sizes[0] / 128;
    const int E = in_sizes[1] / 2;
    const int* src = ei;
    const int* dst = ei + E;

    // Workspace carve-up (all regions fully written before read).
    char* ws = (char*)d_ws;
    auto take = [&](size_t bytes) {
        char* p = ws;
        ws += (bytes + 255) & ~(size_t)255;
        return p;
    };
    float* m   = (float*)take((size_t)N * 128 * sizeof(float));
    float* hA  = (float*)take((size_t)N * 128 * sizeof(float));
    float* hB  = (float*)take((size_t)N * 128 * sizeof(float));
    int* rp      = (int*)take((size_t)(N + 1) * sizeof(int));
    int* cursor  = (int*)take((size_t)N * sizeof(int));
    int* es      = (int*)take((size_t)E * sizeof(int));
    int* partials = (int*)take(4096);

    // ---- CSR build (by dst) ----
    zero_ints<<<ceil_div(N, 256), 256, 0, stream>>>(cursor, N);   // cursor doubles as deg
    hist_kernel<<<ceil_div(E, 256), 256, 0, stream>>>(dst, cursor, E);
    int nScan = ceil_div(N + 1, 256);   // 196 for N=50000 (fits single-block partial scan)
    scan_blocks_kernel<<<nScan, 256, 0, stream>>>(cursor, rp, partials, N + 1, N);
    scan_partials_kernel<<<1, 256, 0, stream>>>(partials, nScan);
    add_offsets_kernel<<<nScan, 256, 0, stream>>>(rp, partials, cursor, N + 1, N);
    fill_kernel<<<ceil_div(E, 256), 256, 0, stream>>>(src, dst, cursor, es, E);

    // ---- Pipeline ----
    const int gemm_grid = ceil_div(N, 32);
    const int agg_grid  = ceil_div(N, 8);

    gemm_bias_kernel<128, 32><<<gemm_grid, 256, 0, stream>>>(x, W1, b1, m, N);
    aggregate_kernel<<<agg_grid, 256, 0, stream>>>(m, rp, es, hA, N, 0);

    gemm_bias_kernel<128, 32><<<gemm_grid, 256, 0, stream>>>(hA, W1, b1, m, N);
    aggregate_kernel<<<agg_grid, 256, 0, stream>>>(m, rp, es, hB, N, 1);   // ReLU

    gemm_bias_kernel<128, 32><<<gemm_grid, 256, 0, stream>>>(hB, W2, b2, m, N);
    aggregate_kernel<<<agg_grid, 256, 0, stream>>>(m, rp, es, hA, N, 0);

    gemm_bias_kernel<128, 32><<<gemm_grid, 256, 0, stream>>>(hA, W2, b2, m, N);
    aggregate_kernel<<<agg_grid, 256, 0, stream>>>(m, rp, es, hB, N, 1);   // ReLU

    gemm_bias_kernel<64, 32><<<gemm_grid, 128, 0, stream>>>(hB, Wout, bout, out, N);
}

// Round 3
// 417.152 us; speedup vs baseline: 1.7975x; 1.2121x over previous
//
#include <hip/hip_runtime.h>
#include <hip/hip_bf16.h>

// ---------------------------------------------------------------------------
// GraphTransformerWithPooling on MI355X (gfx950)
// R3: pool-GEMM writes m as bf16 (halves gather traffic: FETCH 131->~66 MB),
// aggregate gathers bf16 rows with x4-unrolled edge loop (more MLP),
// accumulates fp32. Final GEMM + node features stay fp32 end-to-end.
// ---------------------------------------------------------------------------

static inline int ceil_div(int a, int b) { return (a + b - 1) / b; }

// ---------------- CSR build ----------------

__global__ __launch_bounds__(256) void zero_ints(int* __restrict__ p, int n) {
    int i = blockIdx.x * 256 + threadIdx.x;
    if (i < n) p[i] = 0;
}

__global__ __launch_bounds__(256) void hist_kernel(const int* __restrict__ dst,
                                                   int* __restrict__ deg, int E) {
    int e = blockIdx.x * 256 + threadIdx.x;
    if (e < E) atomicAdd(&deg[dst[e]], 1);
}

__global__ __launch_bounds__(256) void scan_blocks_kernel(const int* __restrict__ deg,
                                                          int* __restrict__ rp,
                                                          int* __restrict__ partials,
                                                          int n, int N) {
    __shared__ int s[256];
    int tid = threadIdx.x;
    int i = blockIdx.x * 256 + tid;
    int v = (i < N) ? deg[i] : 0;
    s[tid] = v;
    __syncthreads();
    for (int off = 1; off < 256; off <<= 1) {
        int t = (tid >= off) ? s[tid - off] : 0;
        __syncthreads();
        s[tid] += t;
        __syncthreads();
    }
    if (i < n) rp[i] = s[tid] - v;
    if (tid == 255) partials[blockIdx.x] = s[255];
}

__global__ __launch_bounds__(256) void scan_partials_kernel(int* __restrict__ partials, int nb) {
    __shared__ int s[256];
    int tid = threadIdx.x;
    int v = (tid < nb) ? partials[tid] : 0;
    s[tid] = v;
    __syncthreads();
    for (int off = 1; off < 256; off <<= 1) {
        int t = (tid >= off) ? s[tid - off] : 0;
        __syncthreads();
        s[tid] += t;
        __syncthreads();
    }
    if (tid < nb) partials[tid] = s[tid] - v;
}

__global__ __launch_bounds__(256) void add_offsets_kernel(int* __restrict__ rp,
                                                          const int* __restrict__ partials,
                                                          int* __restrict__ cursor,
                                                          int n, int N) {
    int i = blockIdx.x * 256 + threadIdx.x;
    if (i < n) {
        int v = rp[i] + partials[blockIdx.x];
        rp[i] = v;
        if (i < N) cursor[i] = v;
    }
}

__global__ __launch_bounds__(256) void fill_kernel(const int* __restrict__ src,
                                                   const int* __restrict__ dst,
                                                   int* __restrict__ cursor,
                                                   int* __restrict__ es, int E) {
    int e = blockIdx.x * 256 + threadIdx.x;
    if (e < E) {
        int p = atomicAdd(&cursor[dst[e]], 1);
        es[p] = src[e];
    }
}

// ---------------- GEMM: Y[n,COLS] = X[n,128] @ W[128,COLS] + B ----------------
// 32-row x COLS tile, 4x4 register tile, W staged in LDS in KC chunks.
// BF16OUT=true writes bf16 rows (feeds the gather); false writes fp32.

template <int COLS, int KC, bool BF16OUT>
__global__ __launch_bounds__(2 * COLS) void gemm_bias_kernel(const float* __restrict__ X,
                                                             const float* __restrict__ W,
                                                             const float* __restrict__ B,
                                                             void* __restrict__ Yv, int n) {
    constexpr int TPB = 2 * COLS;
    constexpr int CG = COLS / 4;
    __shared__ float Wl[KC * COLS];
    __shared__ float Xl[32][132];

    int tid = threadIdx.x;
    int r0 = blockIdx.x * 32;

    for (int idx = tid; idx < 32 * 32; idx += TPB) {
        int r = idx >> 5, c = idx & 31;
        float4 v = make_float4(0.f, 0.f, 0.f, 0.f);
        if (r0 + r < n) v = ((const float4*)(X + (size_t)(r0 + r) * 128))[c];
        *((float4*)&Xl[r][c * 4]) = v;
    }

    int cg = tid % CG, rg = tid / CG;
    int col = cg * 4, row = rg * 4;
    float acc[4][4] = {};

#pragma unroll 1   // do NOT hoist W staging across chunks (R1: 256 VGPR + spills)
    for (int kc = 0; kc < 128; kc += KC) {
        __syncthreads();
        for (int idx = tid; idx < KC * COLS / 4; idx += TPB) {
            ((float4*)Wl)[idx] = ((const float4*)(W + (size_t)kc * COLS))[idx];
        }
        __syncthreads();
#pragma unroll 2   // bound live Wl registers
        for (int k = 0; k < KC; k += 4) {
            float4 w0 = *((float4*)&Wl[(k + 0) * COLS + col]);
            float4 w1 = *((float4*)&Wl[(k + 1) * COLS + col]);
            float4 w2 = *((float4*)&Wl[(k + 2) * COLS + col]);
            float4 w3 = *((float4*)&Wl[(k + 3) * COLS + col]);
#pragma unroll
            for (int r = 0; r < 4; ++r) {
                float4 xv = *((float4*)&Xl[row + r][kc + k]);
                acc[r][0] += xv.x * w0.x + xv.y * w1.x + xv.z * w2.x + xv.w * w3.x;
                acc[r][1] += xv.x * w0.y + xv.y * w1.y + xv.z * w2.y + xv.w * w3.y;
                acc[r][2] += xv.x * w0.z + xv.y * w1.z + xv.z * w2.z + xv.w * w3.z;
                acc[r][3] += xv.x * w0.w + xv.y * w1.w + xv.z * w2.w + xv.w * w3.w;
            }
        }
    }

    float4 bb = *((const float4*)(B + col));
#pragma unroll
    for (int r = 0; r < 4; ++r) {
        int gr = r0 + row + r;
        if (gr < n) {
            float o0 = acc[r][0] + bb.x, o1 = acc[r][1] + bb.y;
            float o2 = acc[r][2] + bb.z, o3 = acc[r][3] + bb.w;
            if (BF16OUT) {
                union { ushort4 u; __hip_bfloat16 h[4]; } p;
                p.h[0] = __float2bfloat16(o0);
                p.h[1] = __float2bfloat16(o1);
                p.h[2] = __float2bfloat16(o2);
                p.h[3] = __float2bfloat16(o3);
                *((ushort4*)((__hip_bfloat16*)Yv + (size_t)gr * COLS + col)) = p.u;
            } else {
                *((float4*)((float*)Yv + (size_t)gr * COLS + col)) =
                    make_float4(o0, o1, o2, o3);
            }
        }
    }
}

// ---------------- Aggregate (bf16 rows): H[i,:] = sum_e M[es[e],:] ----------------
// 16 lanes per node, uint4 = 8 bf16 per lane (row = 256 B). Edge loop unrolled
// x4 for memory-level parallelism; fp32 accumulators; fp32 output (+ReLU).

__device__ inline void acc_row8(float* a, uint4 v) {
    a[0] += __uint_as_float(v.x << 16);
    a[1] += __uint_as_float(v.x & 0xffff0000u);
    a[2] += __uint_as_float(v.y << 16);
    a[3] += __uint_as_float(v.y & 0xffff0000u);
    a[4] += __uint_as_float(v.z << 16);
    a[5] += __uint_as_float(v.z & 0xffff0000u);
    a[6] += __uint_as_float(v.w << 16);
    a[7] += __uint_as_float(v.w & 0xffff0000u);
}

__global__ __launch_bounds__(256) void aggregate_bf16_kernel(const __hip_bfloat16* __restrict__ M,
                                                             const int* __restrict__ rp,
                                                             const int* __restrict__ es,
                                                             float* __restrict__ H,
                                                             int n, int do_relu) {
    int node = blockIdx.x * 16 + (threadIdx.x >> 4);
    int lane = threadIdx.x & 15;
    if (node >= n) return;
    int beg = rp[node], end = rp[node + 1];
    float acc[8] = {};

    int e = beg;
    for (; e + 4 <= end; e += 4) {
        int s0 = es[e], s1 = es[e + 1], s2 = es[e + 2], s3 = es[e + 3];
        uint4 v0 = ((const uint4*)(M + (size_t)s0 * 128))[lane];
        uint4 v1 = ((const uint4*)(M + (size_t)s1 * 128))[lane];
        uint4 v2 = ((const uint4*)(M + (size_t)s2 * 128))[lane];
        uint4 v3 = ((const uint4*)(M + (size_t)s3 * 128))[lane];
        acc_row8(acc, v0);
        acc_row8(acc, v1);
        acc_row8(acc, v2);
        acc_row8(acc, v3);
    }
    for (; e < end; ++e) {
        uint4 v = ((const uint4*)(M + (size_t)es[e] * 128))[lane];
        acc_row8(acc, v);
    }

    if (do_relu) {
#pragma unroll
        for (int i = 0; i < 8; ++i) acc[i] = fmaxf(acc[i], 0.f);
    }
    float* hrow = H + (size_t)node * 128 + lane * 8;
    ((float4*)hrow)[0] = make_float4(acc[0], acc[1], acc[2], acc[3]);
    ((float4*)hrow)[1] = make_float4(acc[4], acc[5], acc[6], acc[7]);
}

// ---------------- Launch ----------------

extern "C" void kernel_launch(void* const* d_in, const int* in_sizes, int n_in,
                              void* d_out, int out_size, void* d_ws, size_t ws_size,
                              hipStream_t stream) {
    const float* x    = (const float*)d_in[0];
    const int*   ei   = (const int*)d_in[1];
    const float* W1   = (const float*)d_in[2];
    const float* b1   = (const float*)d_in[3];
    const float* W2   = (const float*)d_in[4];
    const float* b2   = (const float*)d_in[5];
    const float* Wout = (const float*)d_in[6];
    const float* bout = (const float*)d_in[7];
    float*       out  = (float*)d_out;

    const int N = in_sizes[0] / 128;
    const int E = in_sizes[1] / 2;
    const int* src = ei;
    const int* dst = ei + E;

    char* ws = (char*)d_ws;
    auto take = [&](size_t bytes) {
        char* p = ws;
        ws += (bytes + 255) & ~(size_t)255;
        return p;
    };
    __hip_bfloat16* m = (__hip_bfloat16*)take((size_t)N * 128 * sizeof(__hip_bfloat16));
    float* hA  = (float*)take((size_t)N * 128 * sizeof(float));
    float* hB  = (float*)take((size_t)N * 128 * sizeof(float));
    int* rp      = (int*)take((size_t)(N + 1) * sizeof(int));
    int* cursor  = (int*)take((size_t)N * sizeof(int));
    int* es      = (int*)take((size_t)E * sizeof(int));
    int* partials = (int*)take(4096);

    // ---- CSR build (by dst) ----
    zero_ints<<<ceil_div(N, 256), 256, 0, stream>>>(cursor, N);
    hist_kernel<<<ceil_div(E, 256), 256, 0, stream>>>(dst, cursor, E);
    int nScan = ceil_div(N + 1, 256);
    scan_blocks_kernel<<<nScan, 256, 0, stream>>>(cursor, rp, partials, N + 1, N);
    scan_partials_kernel<<<1, 256, 0, stream>>>(partials, nScan);
    add_offsets_kernel<<<nScan, 256, 0, stream>>>(rp, partials, cursor, N + 1, N);
    fill_kernel<<<ceil_div(E, 256), 256, 0, stream>>>(src, dst, cursor, es, E);

    // ---- Pipeline ----
    const int gemm_grid = ceil_div(N, 32);
    const int agg_grid  = ceil_div(N, 16);

    gemm_bias_kernel<128, 32, true><<<gemm_grid, 256, 0, stream>>>(x, W1, b1, m, N);
    aggregate_bf16_kernel<<<agg_grid, 256, 0, stream>>>(m, rp, es, hA, N, 0);

    gemm_bias_kernel<128, 32, true><<<gemm_grid, 256, 0, stream>>>(hA, W1, b1, m, N);
    aggregate_bf16_kernel<<<agg_grid, 256, 0, stream>>>(m, rp, es, hB, N, 1);   // ReLU

    gemm_bias_kernel<128, 32, true><<<gemm_grid, 256, 0, stream>>>(hB, W2, b2, m, N);
    aggregate_bf16_kernel<<<agg_grid, 256, 0, stream>>>(m, rp, es, hA, N, 0);

    gemm_bias_kernel<128, 32, true><<<gemm_grid, 256, 0, stream>>>(hA, W2, b2, m, N);
    aggregate_bf16_kernel<<<agg_grid, 256, 0, stream>>>(m, rp, es, hB, N, 1);   // ReLU

    gemm_bias_kernel<64, 32, false><<<gemm_grid, 128, 0, stream>>>(hB, Wout, bout, out, N);
}

// Round 4
// 344.662 us; speedup vs baseline: 2.1755x; 1.2103x over previous
//
#include <hip/hip_runtime.h>
#include <hip/hip_bf16.h>

// ---------------------------------------------------------------------------
// GraphTransformerWithPooling on MI355X (gfx950)
// R4: GEMMs moved to bf16 MFMA (16x16x32) with split-precision weights
// (W = Whi + Wlo, both bf16; D = A*Whi + A*Wlo, fp32 accum) so only A's bf16
// rounding contributes error. All inter-stage tensors bf16. GEMM kernel is
// LDS-free/barrier-free: A frags gathered to regs, W frags streamed from a
// pre-expanded fragment-layout array (L2-resident, same 64 KB for all blocks).
// ---------------------------------------------------------------------------

static inline int ceil_div(int a, int b) { return (a + b - 1) / b; }

typedef __attribute__((ext_vector_type(8))) short bf16x8;  // MFMA A/B frag (4 VGPRs)
typedef __attribute__((ext_vector_type(4))) float f32x4;   // MFMA C/D frag

__device__ inline unsigned short f2bf(float f) {   // fp32 -> bf16 RNE
    unsigned u = __float_as_uint(f);
    return (unsigned short)((u + 0x7fffu + ((u >> 16) & 1u)) >> 16);
}
__device__ inline float bf2f(unsigned short h) {
    return __uint_as_float(((unsigned)h) << 16);
}

// ---------------- CSR build ----------------

__global__ __launch_bounds__(256) void zero_ints(int* __restrict__ p, int n) {
    int i = blockIdx.x * 256 + threadIdx.x;
    if (i < n) p[i] = 0;
}

__global__ __launch_bounds__(256) void hist_kernel(const int* __restrict__ dst,
                                                   int* __restrict__ deg, int E) {
    int e = blockIdx.x * 256 + threadIdx.x;
    if (e < E) atomicAdd(&deg[dst[e]], 1);
}

__global__ __launch_bounds__(256) void scan_blocks_kernel(const int* __restrict__ deg,
                                                          int* __restrict__ rp,
                                                          int* __restrict__ partials,
                                                          int n, int N) {
    __shared__ int s[256];
    int tid = threadIdx.x;
    int i = blockIdx.x * 256 + tid;
    int v = (i < N) ? deg[i] : 0;
    s[tid] = v;
    __syncthreads();
    for (int off = 1; off < 256; off <<= 1) {
        int t = (tid >= off) ? s[tid - off] : 0;
        __syncthreads();
        s[tid] += t;
        __syncthreads();
    }
    if (i < n) rp[i] = s[tid] - v;
    if (tid == 255) partials[blockIdx.x] = s[255];
}

__global__ __launch_bounds__(256) void scan_partials_kernel(int* __restrict__ partials, int nb) {
    __shared__ int s[256];
    int tid = threadIdx.x;
    int v = (tid < nb) ? partials[tid] : 0;
    s[tid] = v;
    __syncthreads();
    for (int off = 1; off < 256; off <<= 1) {
        int t = (tid >= off) ? s[tid - off] : 0;
        __syncthreads();
        s[tid] += t;
        __syncthreads();
    }
    if (tid < nb) partials[tid] = s[tid] - v;
}

__global__ __launch_bounds__(256) void add_offsets_kernel(int* __restrict__ rp,
                                                          const int* __restrict__ partials,
                                                          int* __restrict__ cursor,
                                                          int n, int N) {
    int i = blockIdx.x * 256 + threadIdx.x;
    if (i < n) {
        int v = rp[i] + partials[blockIdx.x];
        rp[i] = v;
        if (i < N) cursor[i] = v;
    }
}

__global__ __launch_bounds__(256) void fill_kernel(const int* __restrict__ src,
                                                   const int* __restrict__ dst,
                                                   int* __restrict__ cursor,
                                                   int* __restrict__ es, int E) {
    int e = blockIdx.x * 256 + threadIdx.x;
    if (e < E) {
        int p = atomicAdd(&cursor[dst[e]], 1);
        es[p] = src[e];
    }
}

// ---------------- W prep: expand fp32 W[K][C] -> hi/lo bf16 frag arrays ------
// Frag layout t = ((ct*4 + c)*64 + lane)*8 + j  maps to
//   k = c*32 + (lane>>4)*8 + j,  col = ct*16 + (lane&15)
// so a wave's ds-free 16B load Whi[(ct*4+c)*64 + lane] is the MFMA B fragment.

__global__ __launch_bounds__(256) void wprep_kernel(const float* __restrict__ W,
                                                    unsigned short* __restrict__ hi,
                                                    unsigned short* __restrict__ lo,
                                                    int total, int C) {
    int t = blockIdx.x * 256 + threadIdx.x;
    if (t >= total) return;
    int j = t & 7;
    int lane = (t >> 3) & 63;
    int f = t >> 9;           // frag id = ct*4 + c
    int c = f & 3, ct = f >> 2;
    int k = c * 32 + (lane >> 4) * 8 + j;
    int col = ct * 16 + (lane & 15);
    float w = W[(size_t)k * C + col];
    unsigned short h = f2bf(w);
    hi[t] = h;
    lo[t] = f2bf(w - bf2f(h));
}

// ---------------- MFMA GEMM: Y[n,COLS] = A[n,128] @ (Whi+Wlo) + B -----------
// Block = 256 thr = 4 waves; block covers 64 rows x COLS cols.
// Wave covers 64 rows x (COLS/4) cols = 4 row-tiles x CT_W col-tiles.
// No LDS, no barriers. A frags held in regs (16x bf16x8), W frags streamed.

template <int COLS, bool AF32, bool OUTF32>
__global__ __launch_bounds__(256) void gemm_mfma_kernel(const void* __restrict__ Av,
                                                        const uint4* __restrict__ Whi,
                                                        const uint4* __restrict__ Wlo,
                                                        const float* __restrict__ Bias,
                                                        void* __restrict__ Yv, int n) {
    constexpr int CT_W = COLS / 64;   // col-tiles per wave (128->2, 64->1)
    int tid = threadIdx.x;
    int wave = tid >> 6, lane = tid & 63;
    int lm = lane & 15, lq = lane >> 4;
    int r0 = blockIdx.x * 64;

    // ---- A fragments: 4 row-tiles x 4 K-chunks, 16 B per lane each ----
    bf16x8 afr[4][4];
#pragma unroll
    for (int rt = 0; rt < 4; ++rt) {
        int ar = r0 + rt * 16 + lm;
        if (ar > n - 1) ar = n - 1;          // clamp; stores are guarded
#pragma unroll
        for (int c = 0; c < 4; ++c) {
            int k = c * 32 + lq * 8;
            if (AF32) {
                const float* ap = (const float*)Av + (size_t)ar * 128 + k;
                float4 f0 = ((const float4*)ap)[0];
                float4 f1 = ((const float4*)ap)[1];
                bf16x8 v;
                v[0] = (short)f2bf(f0.x); v[1] = (short)f2bf(f0.y);
                v[2] = (short)f2bf(f0.z); v[3] = (short)f2bf(f0.w);
                v[4] = (short)f2bf(f1.x); v[5] = (short)f2bf(f1.y);
                v[6] = (short)f2bf(f1.z); v[7] = (short)f2bf(f1.w);
                afr[rt][c] = v;
            } else {
                uint4 u = *(const uint4*)((const unsigned short*)Av + (size_t)ar * 128 + k);
                afr[rt][c] = *(const bf16x8*)&u;
            }
        }
    }

    f32x4 acc[4][CT_W];
#pragma unroll
    for (int rt = 0; rt < 4; ++rt)
#pragma unroll
        for (int t = 0; t < CT_W; ++t)
            acc[rt][t] = (f32x4){0.f, 0.f, 0.f, 0.f};

    // ---- main MFMA loop: D += A*Whi + A*Wlo ----
#pragma unroll
    for (int c = 0; c < 4; ++c) {
#pragma unroll
        for (int t = 0; t < CT_W; ++t) {
            int ct = wave * CT_W + t;
            uint4 uh = Whi[(ct * 4 + c) * 64 + lane];
            uint4 ul = Wlo[(ct * 4 + c) * 64 + lane];
            bf16x8 wh = *(const bf16x8*)&uh;
            bf16x8 wl = *(const bf16x8*)&ul;
#pragma unroll
            for (int rt = 0; rt < 4; ++rt) {
                acc[rt][t] = __builtin_amdgcn_mfma_f32_16x16x32_bf16(afr[rt][c], wh, acc[rt][t], 0, 0, 0);
                acc[rt][t] = __builtin_amdgcn_mfma_f32_16x16x32_bf16(afr[rt][c], wl, acc[rt][t], 0, 0, 0);
            }
        }
    }

    // ---- epilogue: +bias, store (C/D layout: col=lane&15, row=lq*4+reg) ----
#pragma unroll
    for (int t = 0; t < CT_W; ++t) {
        int col = (wave * CT_W + t) * 16 + lm;
        float bias = Bias[col];
#pragma unroll
        for (int rt = 0; rt < 4; ++rt) {
#pragma unroll
            for (int r = 0; r < 4; ++r) {
                int row = r0 + rt * 16 + lq * 4 + r;
                if (row < n) {
                    float v = acc[rt][t][r] + bias;
                    if (OUTF32)
                        ((float*)Yv)[(size_t)row * COLS + col] = v;
                    else
                        ((unsigned short*)Yv)[(size_t)row * COLS + col] = f2bf(v);
                }
            }
        }
    }
}

// ---------------- Aggregate (bf16 in, fp32 acc, bf16 out) -------------------
// 16 lanes per node, uint4 = 8 bf16 per lane. Edge loop x4 unrolled for MLP.

__device__ inline void acc_row8(float* a, uint4 v) {
    a[0] += __uint_as_float(v.x << 16);
    a[1] += __uint_as_float(v.x & 0xffff0000u);
    a[2] += __uint_as_float(v.y << 16);
    a[3] += __uint_as_float(v.y & 0xffff0000u);
    a[4] += __uint_as_float(v.z << 16);
    a[5] += __uint_as_float(v.z & 0xffff0000u);
    a[6] += __uint_as_float(v.w << 16);
    a[7] += __uint_as_float(v.w & 0xffff0000u);
}

__global__ __launch_bounds__(256) void aggregate_bf16_kernel(const unsigned short* __restrict__ M,
                                                             const int* __restrict__ rp,
                                                             const int* __restrict__ es,
                                                             unsigned short* __restrict__ H,
                                                             int n, int do_relu) {
    int node = blockIdx.x * 16 + (threadIdx.x >> 4);
    int lane = threadIdx.x & 15;
    if (node >= n) return;
    int beg = rp[node], end = rp[node + 1];
    float acc[8] = {};

    int e = beg;
    for (; e + 4 <= end; e += 4) {
        int s0 = es[e], s1 = es[e + 1], s2 = es[e + 2], s3 = es[e + 3];
        uint4 v0 = ((const uint4*)(M + (size_t)s0 * 128))[lane];
        uint4 v1 = ((const uint4*)(M + (size_t)s1 * 128))[lane];
        uint4 v2 = ((const uint4*)(M + (size_t)s2 * 128))[lane];
        uint4 v3 = ((const uint4*)(M + (size_t)s3 * 128))[lane];
        acc_row8(acc, v0);
        acc_row8(acc, v1);
        acc_row8(acc, v2);
        acc_row8(acc, v3);
    }
    for (; e < end; ++e) {
        uint4 v = ((const uint4*)(M + (size_t)es[e] * 128))[lane];
        acc_row8(acc, v);
    }

    if (do_relu) {
#pragma unroll
        for (int i = 0; i < 8; ++i) acc[i] = fmaxf(acc[i], 0.f);
    }
    uint4 o;
    o.x = (unsigned)f2bf(acc[0]) | ((unsigned)f2bf(acc[1]) << 16);
    o.y = (unsigned)f2bf(acc[2]) | ((unsigned)f2bf(acc[3]) << 16);
    o.z = (unsigned)f2bf(acc[4]) | ((unsigned)f2bf(acc[5]) << 16);
    o.w = (unsigned)f2bf(acc[6]) | ((unsigned)f2bf(acc[7]) << 16);
    *(uint4*)(H + (size_t)node * 128 + lane * 8) = o;
}

// ---------------- Launch ----------------

extern "C" void kernel_launch(void* const* d_in, const int* in_sizes, int n_in,
                              void* d_out, int out_size, void* d_ws, size_t ws_size,
                              hipStream_t stream) {
    const float* x    = (const float*)d_in[0];
    const int*   ei   = (const int*)d_in[1];
    const float* W1   = (const float*)d_in[2];
    const float* b1   = (const float*)d_in[3];
    const float* W2   = (const float*)d_in[4];
    const float* b2   = (const float*)d_in[5];
    const float* Wout = (const float*)d_in[6];
    const float* bout = (const float*)d_in[7];
    float*       out  = (float*)d_out;

    const int N = in_sizes[0] / 128;
    const int E = in_sizes[1] / 2;
    const int* src = ei;
    const int* dst = ei + E;

    char* ws = (char*)d_ws;
    auto take = [&](size_t bytes) {
        char* p = ws;
        ws += (bytes + 255) & ~(size_t)255;
        return p;
    };
    unsigned short* m  = (unsigned short*)take((size_t)N * 128 * 2);
    unsigned short* hA = (unsigned short*)take((size_t)N * 128 * 2);
    unsigned short* hB = (unsigned short*)take((size_t)N * 128 * 2);
    unsigned short* W1hi = (unsigned short*)take(128 * 128 * 2);
    unsigned short* W1lo = (unsigned short*)take(128 * 128 * 2);
    unsigned short* W2hi = (unsigned short*)take(128 * 128 * 2);
    unsigned short* W2lo = (unsigned short*)take(128 * 128 * 2);
    unsigned short* Wohi = (unsigned short*)take(128 * 64 * 2);
    unsigned short* Wolo = (unsigned short*)take(128 * 64 * 2);
    int* rp      = (int*)take((size_t)(N + 1) * sizeof(int));
    int* cursor  = (int*)take((size_t)N * sizeof(int));
    int* es      = (int*)take((size_t)E * sizeof(int));
    int* partials = (int*)take(4096);

    // ---- CSR build (by dst) ----
    zero_ints<<<ceil_div(N, 256), 256, 0, stream>>>(cursor, N);
    hist_kernel<<<ceil_div(E, 256), 256, 0, stream>>>(dst, cursor, E);
    int nScan = ceil_div(N + 1, 256);
    scan_blocks_kernel<<<nScan, 256, 0, stream>>>(cursor, rp, partials, N + 1, N);
    scan_partials_kernel<<<1, 256, 0, stream>>>(partials, nScan);
    add_offsets_kernel<<<nScan, 256, 0, stream>>>(rp, partials, cursor, N + 1, N);
    fill_kernel<<<ceil_div(E, 256), 256, 0, stream>>>(src, dst, cursor, es, E);

    // ---- W split-precision frag expansion (once) ----
    wprep_kernel<<<64, 256, 0, stream>>>(W1, W1hi, W1lo, 128 * 128, 128);
    wprep_kernel<<<64, 256, 0, stream>>>(W2, W2hi, W2lo, 128 * 128, 128);
    wprep_kernel<<<32, 256, 0, stream>>>(Wout, Wohi, Wolo, 128 * 64, 64);

    // ---- Pipeline ----
    const int gemm_grid = ceil_div(N, 64);
    const int agg_grid  = ceil_div(N, 16);

    gemm_mfma_kernel<128, true, false><<<gemm_grid, 256, 0, stream>>>(
        x, (const uint4*)W1hi, (const uint4*)W1lo, b1, m, N);
    aggregate_bf16_kernel<<<agg_grid, 256, 0, stream>>>(m, rp, es, hA, N, 0);

    gemm_mfma_kernel<128, false, false><<<gemm_grid, 256, 0, stream>>>(
        hA, (const uint4*)W1hi, (const uint4*)W1lo, b1, m, N);
    aggregate_bf16_kernel<<<agg_grid, 256, 0, stream>>>(m, rp, es, hB, N, 1);   // ReLU

    gemm_mfma_kernel<128, false, false><<<gemm_grid, 256, 0, stream>>>(
        hB, (const uint4*)W2hi, (const uint4*)W2lo, b2, m, N);
    aggregate_bf16_kernel<<<agg_grid, 256, 0, stream>>>(m, rp, es, hA, N, 0);

    gemm_mfma_kernel<128, false, false><<<gemm_grid, 256, 0, stream>>>(
        hA, (const uint4*)W2hi, (const uint4*)W2lo, b2, m, N);
    aggregate_bf16_kernel<<<agg_grid, 256, 0, stream>>>(m, rp, es, hB, N, 1);   // ReLU

    gemm_mfma_kernel<64, false, true><<<gemm_grid, 256, 0, stream>>>(
        hB, (const uint4*)Wohi, (const uint4*)Wolo, bout, out, N);
}